// Round 14
// baseline (208.359 us; speedup 1.0000x reference)
//
#include <hip/hip_runtime.h>
#include <hip/hip_bf16.h>

typedef short bf16x8 __attribute__((ext_vector_type(8)));
typedef float f32x4  __attribute__((ext_vector_type(4)));
typedef unsigned int u32x4 __attribute__((ext_vector_type(4)));

#define LOG2E 1.44269504088896340736f

static __device__ __forceinline__ unsigned short f2bf(float f){
    __hip_bfloat16 h = __float2bfloat16(f);
    return __builtin_bit_cast(unsigned short, h);
}
static __device__ __forceinline__ unsigned pk_bf16(float lo, float hi){
    return (((unsigned)f2bf(hi)) << 16) | (unsigned)f2bf(lo);
}
static __device__ __forceinline__ float rcp_(float x){ return __builtin_amdgcn_rcpf(x); }
static __device__ __forceinline__ float ex2(float x){ return __builtin_amdgcn_exp2f(x); }
static __device__ __forceinline__ void lds_fence(){
    asm volatile("s_waitcnt lgkmcnt(0)" ::: "memory");
}
static __device__ __forceinline__ f32x4 mfma16(bf16x8 a, bf16x8 b, f32x4 c){
    return __builtin_amdgcn_mfma_f32_16x16x32_bf16(a, b, c, 0, 0, 0);
}
static __device__ __forceinline__ unsigned swz8(unsigned v){
    // lane l <-> lane l^8 (BitMode xor_mask=8)
    return (unsigned)__builtin_amdgcn_ds_swizzle((int)v, 0x201F);
}
static __device__ __forceinline__ unsigned relu_pk(unsigned v){
    unsigned m = ((v >> 15) & 0x00010001u) * 0xFFFFu;
    return v & ~m;
}

__global__ void marker_kernel(float* out, int n, float v){
    int i = blockIdx.x * 256 + threadIdx.x;
    if (i < n) out[i] = v;
}

// v5: 8 rows/wave (cols duplicate batch), half-trans per lane (ch = c>>3),
// 2 waves/SIMD. The lane^8 h-exchange (ds_swizzle) is taken OFF the critical
// path: every h-MFMA is split into own-half + partner-half with zero-padded
// B-fragments; own-half MFMAs issue while the swizzle is in flight, only the
// partner-half group waits on lgkmcnt.
__global__ __launch_bounds__(256, 2)
void vae_mfma5_kernel(const float* __restrict__ x,      const float* __restrict__ eps,
                      const float* __restrict__ eWih,   const float* __restrict__ eWhh,
                      const float* __restrict__ ebih,   const float* __restrict__ ebhh,
                      const float* __restrict__ Wmu,    const float* __restrict__ bmu,
                      const float* __restrict__ Wlv,    const float* __restrict__ blv,
                      const float* __restrict__ Wl2h,   const float* __restrict__ bl2h,
                      const float* __restrict__ Wl2h2,  const float* __restrict__ bl2h2,
                      const float* __restrict__ stok,   const float* __restrict__ Wemb,
                      const float* __restrict__ bemb,
                      const float* __restrict__ dWih,   const float* __restrict__ dWhh,
                      const float* __restrict__ dbih,   const float* __restrict__ dbhh,
                      const float* __restrict__ Wout,   const float* __restrict__ bout,
                      const float* __restrict__ Wseq,   const float* __restrict__ bseq,
                      const float* __restrict__ Wseq2,  const float* __restrict__ bseq2,
                      float* __restrict__ recon,
                      float* __restrict__ out_mu,
                      float* __restrict__ out_lv,
                      float* __restrict__ out_num)
{
    __shared__ float hbf[4][8][33];
    __shared__ float cbf[4][8][33];
    __shared__ float mubuf[4][8];
    __shared__ float x0buf[4][32];
    __shared__ float cw[524];
    // cw: 0 Wmu[64] | 64 Wlv[64] | 128 Wseq[32] | 160 bseq[32] | 192 Wseq2[32]
    //     224 Wl2h[32] | 256 bl2h[32] | 288 Wl2h2[32] | 320 bl2h2[32]
    //     352 Wout[160] | 512 bout[5] | 517 bmu | 518 blv | 519 bseq2

    const int tid = threadIdx.x;
    const int w   = tid >> 6;
    const int l   = tid & 63;
    const int c   = l & 15;      // MFMA col
    const int g   = l >> 4;      // k-chunk / D row-group
    const int ch  = c >> 3;      // unit-half owned by this lane
    const int bb  = c & 7;       // batch row within wave
    const int bbase = blockIdx.x * 32 + w * 8;

    if (tid < 64){ cw[tid] = Wmu[tid]; cw[64+tid] = Wlv[tid]; }
    if (tid < 32){
        cw[128+tid] = Wseq[tid];  cw[160+tid] = bseq[tid];  cw[192+tid] = Wseq2[tid];
        cw[224+tid] = Wl2h[tid];  cw[256+tid] = bl2h[tid];
        cw[288+tid] = Wl2h2[tid]; cw[320+tid] = bl2h2[tid];
    }
    if (tid < 160) cw[352+tid] = Wout[tid];
    if (tid < 5)   cw[512+tid] = bout[tid];
    if (tid == 0){ cw[517] = bmu[0]; cw[518] = blv[0]; cw[519] = bseq2[0]; }
    __syncthreads();

    // ---- encoder fragments: A = W, GR(n,r) = gt*32 + (r>>2)*8 + half*4 + (r&3) ----
    bf16x8 WH[8], WX[8];
    f32x4  biasv[8];
    #pragma unroll
    for (int n=0;n<8;++n){
        const int gt = n>>1, half = n&1;
        const float sc = (gt==2) ? (-2.0f*LOG2E) : (-LOG2E);
        const int GRc = gt*32 + ((c>>2)<<3) + half*4 + (c&3);
        bf16x8 t;
        #pragma unroll
        for (int j=0;j<8;++j) t[j] = (short)f2bf(sc * eWhh[(size_t)GRc*32 + g*8 + j]);
        WH[n] = t;
        bf16x8 tx = (bf16x8)0;
        if (g == 0){
            #pragma unroll
            for (int j=0;j<5;++j) tx[j] = (short)f2bf(sc * eWih[(size_t)GRc*5 + j]);
        }
        WX[n] = tx;
        f32x4 b4;
        #pragma unroll
        for (int q=0;q<4;++q){
            const int R = gt*32 + g*8 + half*4 + q;
            b4[q] = sc * (ebih[R] + ebhh[R]);
        }
        biasv[n] = b4;
    }

    float cs[4], hn[4];
    #pragma unroll
    for (int k=0;k<4;++k){ cs[k] = 0.0f; hn[k] = 0.0f; }
    unsigned wA = 0u, wB = 0u, pA = 0u, pB = 0u;

    float4 xA = {0,0,0,0}; float xB = 0.0f;
    if (g == 0){
        const float* xp = x + (size_t)(bbase+bb)*500;
        xA = *(const float4*)xp; xB = xp[4];
    }

    // ================= encoder LSTM (T=100) =================
    for (int t=0; t<100; ++t){
        // assemble split h fragments (own: words ch*2..+1; partner: (1-ch)*2..+1)
        u32x4 ow, pr;
        ow[0] = ch ? 0u : wA;  ow[1] = ch ? 0u : wB;
        ow[2] = ch ? wA : 0u;  ow[3] = ch ? wB : 0u;
        pr[0] = ch ? pA : 0u;  pr[1] = ch ? pB : 0u;
        pr[2] = ch ? 0u : pA;  pr[3] = ch ? 0u : pB;
        bf16x8 bh_o = __builtin_bit_cast(bf16x8, ow);
        bf16x8 bh_p = __builtin_bit_cast(bf16x8, pr);

        bf16x8 bx = (bf16x8)0;
        if (g == 0){
            bx[0]=(short)f2bf(xA.x); bx[1]=(short)f2bf(xA.y);
            bx[2]=(short)f2bf(xA.z); bx[3]=(short)f2bf(xA.w);
            bx[4]=(short)f2bf(xB);
            if (t < 99){
                const float* xp = x + (size_t)(bbase+bb)*500 + (t+1)*5;
                xA = *(const float4*)xp; xB = xp[4];
            }
        }

        f32x4 acc[8];
        #pragma unroll
        for (int n=0;n<8;++n) acc[n] = mfma16(WX[n], bx, biasv[n]);
        #pragma unroll
        for (int n=0;n<8;++n) acc[n] = mfma16(WH[n], bh_o, acc[n]);   // no wait
        #pragma unroll
        for (int n=0;n<8;++n) acc[n] = mfma16(WH[n], bh_p, acc[n]);   // waits on swizzle

        f32x4 ai = ch ? acc[1] : acc[0];
        f32x4 af = ch ? acc[3] : acc[2];
        f32x4 ag = ch ? acc[5] : acc[4];
        f32x4 ao = ch ? acc[7] : acc[6];

        #pragma unroll
        for (int q=0;q<4;++q){
            float ei = ex2(ai[q]);      // e^{-i}
            float ef = ex2(af[q]);      // e^{-f}
            float eg = ex2(ag[q]);      // e^{-2g}
            float eo = ex2(ao[q]);      // e^{-o}
            float pig = (1.0f+ei)*(1.0f+eg);
            float num = cs[q]*pig + (1.0f+ef)*(1.0f-eg);
            float cn  = num * rcp_((1.0f+ef)*pig);
            float ec  = ex2(cn * (-2.0f*LOG2E));
            hn[q]     = (1.0f-ec) * rcp_((1.0f+eo)*(1.0f+ec));
            cs[q]     = cn;
        }
        wA = pk_bf16(hn[0], hn[1]);
        wB = pk_bf16(hn[2], hn[3]);
        pA = swz8(wA);                   // in flight across the loop edge
        pB = swz8(wB);
    }

    // ---- h_n / c_n (own 4 units) to LDS for the heads ----
    #pragma unroll
    for (int q=0;q<4;++q){
        const int U = g*8 + ch*4 + q;
        hbf[w][bb][U] = hn[q];
        cbf[w][bb][U] = cs[q];
    }
    lds_fence();

    // ---- decoder fragments ----
    bf16x8 WI[8], WHd[8];
    f32x4  dbias[8];
    #pragma unroll
    for (int n=0;n<8;++n){
        const int gt = n>>1, half = n&1;
        const float sc = (gt==2) ? (-2.0f*LOG2E) : (-LOG2E);
        const int GRc = gt*32 + ((c>>2)<<3) + half*4 + (c&3);
        bf16x8 ti, th;
        #pragma unroll
        for (int j=0;j<8;++j){
            ti[j] = (short)f2bf(sc * dWih[(size_t)GRc*32 + g*8 + j]);
            th[j] = (short)f2bf(sc * dWhh[(size_t)GRc*32 + g*8 + j]);
        }
        WI[n] = ti; WHd[n] = th;
        f32x4 b4;
        #pragma unroll
        for (int q=0;q<4;++q){
            const int R = gt*32 + g*8 + half*4 + q;
            b4[q] = sc * (dbih[R] + dbhh[R]);
        }
        dbias[n] = b4;
    }
    bf16x8 WO = (bf16x8)0;
    f32x4 bosv = (f32x4)0;
    if (c < 5){
        bf16x8 to;
        #pragma unroll
        for (int j=0;j<8;++j) to[j] = (short)f2bf(Wout[c*32 + g*8 + j]);
        WO = to;
    }
    #pragma unroll
    for (int q=0;q<4;++q){
        const int dd = g*4 + q;
        bosv[q] = (dd < 5) ? bout[dd] : 0.0f;
    }

    // ---- heads: mu / logvar / num (lanes 0..7) ----
    if (l < 8){
        const int r = l;
        float mu = cw[517], lv = cw[518];
        #pragma unroll
        for (int k=0;k<32;++k){
            float hvv = hbf[w][r][k], cvv = cbf[w][r][k];
            mu += hvv*cw[k]    + cvv*cw[32+k];
            lv += hvv*cw[64+k] + cvv*cw[96+k];
        }
        out_mu[bbase+r] = mu;
        out_lv[bbase+r] = lv;
        mubuf[w][r] = mu;
        float z = mu + eps[bbase+r] * __builtin_amdgcn_exp2f(0.5f*LOG2E*lv);
        float a2 = cw[519];
        #pragma unroll
        for (int j=0;j<32;++j){
            float s = z*cw[128+j] + cw[160+j];
            s = s > 0.0f ? s : 0.01f*s;
            a2 += cw[192+j]*s;
        }
        out_num[bbase+r] = fmaxf(a2, 0.0f);
    }
    if (l < 32){
        float v = bemb[l];
        #pragma unroll
        for (int d=0; d<5; ++d) v += stok[d]*Wemb[l*5 + d];
        x0buf[w][l] = fmaxf(v, 0.0f);
    }
    lds_fence();

    // ---- decoder init: compute all 8 units locally (no exchange needed) ----
    {
        const float muv = mubuf[w][bb];
        float h8[8];
        #pragma unroll
        for (int ul=0; ul<8; ++ul){
            const int U = g*8 + ul;
            float a = muv*cw[224+U] + cw[256+U];
            h8[ul] = (a > 0.0f ? a : 0.01f*a);
        }
        #pragma unroll
        for (int q=0;q<4;++q){
            const int U = g*8 + ch*4 + q;
            float b = muv*cw[288+U] + cw[320+U];
            cs[q] = (b > 0.0f ? b : 0.01f*b);
        }
        // own half = units ch*4..+3 ; partner half = the other 4 (identical to
        // what the partner lane computes -- same formula, same mu)
        wA = ch ? pk_bf16(h8[4], h8[5]) : pk_bf16(h8[0], h8[1]);
        wB = ch ? pk_bf16(h8[6], h8[7]) : pk_bf16(h8[2], h8[3]);
        pA = ch ? pk_bf16(h8[0], h8[1]) : pk_bf16(h8[4], h8[5]);
        pB = ch ? pk_bf16(h8[2], h8[3]) : pk_bf16(h8[6], h8[7]);
    }
    bf16x8 bx0;
    #pragma unroll
    for (int j=0;j<8;++j) bx0[j] = (short)f2bf(x0buf[w][g*8 + j]);

    // ================= decoder LSTM (T=100, autoregressive) =================
    for (int t=0; t<100; ++t){
        u32x4 ow, pr;
        ow[0] = ch ? 0u : wA;  ow[1] = ch ? 0u : wB;
        ow[2] = ch ? wA : 0u;  ow[3] = ch ? wB : 0u;
        pr[0] = ch ? pA : 0u;  pr[1] = ch ? pB : 0u;
        pr[2] = ch ? 0u : pA;  pr[3] = ch ? 0u : pB;
        bf16x8 bh_o = __builtin_bit_cast(bf16x8, ow);
        bf16x8 bh_p = __builtin_bit_cast(bf16x8, pr);

        // relu'd x fragments (split the same way)
        u32x4 rxo, rxp;
        rxo[0] = relu_pk(ow[0]); rxo[1] = relu_pk(ow[1]);
        rxo[2] = relu_pk(ow[2]); rxo[3] = relu_pk(ow[3]);
        rxp[0] = relu_pk(pr[0]); rxp[1] = relu_pk(pr[1]);
        rxp[2] = relu_pk(pr[2]); rxp[3] = relu_pk(pr[3]);
        bf16x8 bx_o = __builtin_bit_cast(bf16x8, rxo);
        bf16x8 bx_p = __builtin_bit_cast(bf16x8, rxp);

        f32x4 acc[8];
        if (t == 0){
            #pragma unroll
            for (int n=0;n<8;++n) acc[n] = mfma16(WI[n], bx0, dbias[n]);
        } else {
            #pragma unroll
            for (int n=0;n<8;++n) acc[n] = mfma16(WI[n], bx_o, dbias[n]);
        }
        #pragma unroll
        for (int n=0;n<8;++n) acc[n] = mfma16(WHd[n], bh_o, acc[n]);   // no wait
        f32x4 aoo;
        if (t > 0) aoo = mfma16(WO, bh_o, bosv);
        if (t > 0){
            #pragma unroll
            for (int n=0;n<8;++n) acc[n] = mfma16(WI[n], bx_p, acc[n]); // waits
        }
        #pragma unroll
        for (int n=0;n<8;++n) acc[n] = mfma16(WHd[n], bh_p, acc[n]);
        if (t > 0){
            aoo = mfma16(WO, bh_p, aoo);
            if (c < 8){
                float* rp = recon + (size_t)(bbase+bb)*500 + (t-1)*5;
                if (g == 0){ rp[0]=aoo[0]; rp[1]=aoo[1]; rp[2]=aoo[2]; rp[3]=aoo[3]; }
                else if (g == 1){ rp[4]=aoo[0]; }
            }
        }

        f32x4 ai = ch ? acc[1] : acc[0];
        f32x4 af = ch ? acc[3] : acc[2];
        f32x4 ag = ch ? acc[5] : acc[4];
        f32x4 ao = ch ? acc[7] : acc[6];

        #pragma unroll
        for (int q=0;q<4;++q){
            float ei = ex2(ai[q]);
            float ef = ex2(af[q]);
            float eg = ex2(ag[q]);
            float eo = ex2(ao[q]);
            float pig = (1.0f+ei)*(1.0f+eg);
            float num = cs[q]*pig + (1.0f+ef)*(1.0f-eg);
            float cn  = num * rcp_((1.0f+ef)*pig);
            float ec  = ex2(cn * (-2.0f*LOG2E));
            hn[q]     = (1.0f-ec) * rcp_((1.0f+eo)*(1.0f+ec));
            cs[q]     = cn;
        }
        wA = pk_bf16(hn[0], hn[1]);
        wB = pk_bf16(hn[2], hn[3]);
        pA = swz8(wA);
        pB = swz8(wB);
    }

    // final recon row 99 from h_100
    {
        u32x4 ow, pr;
        ow[0] = ch ? 0u : wA;  ow[1] = ch ? 0u : wB;
        ow[2] = ch ? wA : 0u;  ow[3] = ch ? wB : 0u;
        pr[0] = ch ? pA : 0u;  pr[1] = ch ? pB : 0u;
        pr[2] = ch ? 0u : pA;  pr[3] = ch ? 0u : pB;
        f32x4 aoo = mfma16(WO, __builtin_bit_cast(bf16x8, ow), bosv);
        aoo = mfma16(WO, __builtin_bit_cast(bf16x8, pr), aoo);
        if (c < 8){
            float* rp = recon + (size_t)(bbase+bb)*500 + 99*5;
            if (g == 0){ rp[0]=aoo[0]; rp[1]=aoo[1]; rp[2]=aoo[2]; rp[3]=aoo[3]; }
            else if (g == 1){ rp[4]=aoo[0]; }
        }
    }
}

extern "C" void kernel_launch(void* const* d_in, const int* in_sizes, int n_in,
                              void* d_out, int out_size, void* d_ws, size_t ws_size,
                              hipStream_t stream)
{
    (void)d_ws; (void)ws_size;
    static const int EXPECT[27] = {8192000,16384,640,4096,128,128,64,1,64,1,
                                   32,32,32,32,5,160,32,4096,4096,128,128,
                                   160,5,32,32,32,1};
    bool in_ok = (n_in == 27);
    if (in_ok) for (int i = 0; i < 27; ++i) in_ok = in_ok && (in_sizes[i] == EXPECT[i]);
    bool out_ok = (out_size == 8241152);

    float* out = (float*)d_out;
    if (!in_ok){
        marker_kernel<<<(out_size + 255)/256, 256, 0, stream>>>(out, out_size, 2.0f);
        return;
    }
    if (!out_ok){
        marker_kernel<<<(out_size + 255)/256, 256, 0, stream>>>(out, out_size, 3.0f);
        return;
    }

    const float* x     = (const float*)d_in[0];
    const float* eps   = (const float*)d_in[1];
    const float* eWih  = (const float*)d_in[2];
    const float* eWhh  = (const float*)d_in[3];
    const float* ebih  = (const float*)d_in[4];
    const float* ebhh  = (const float*)d_in[5];
    const float* Wmu   = (const float*)d_in[6];
    const float* bmu   = (const float*)d_in[7];
    const float* Wlv   = (const float*)d_in[8];
    const float* blv   = (const float*)d_in[9];
    const float* Wl2h  = (const float*)d_in[10];
    const float* bl2h  = (const float*)d_in[11];
    const float* Wl2h2 = (const float*)d_in[12];
    const float* bl2h2 = (const float*)d_in[13];
    const float* stok  = (const float*)d_in[14];
    const float* Wemb  = (const float*)d_in[15];
    const float* bemb  = (const float*)d_in[16];
    const float* dWih  = (const float*)d_in[17];
    const float* dWhh  = (const float*)d_in[18];
    const float* dbih  = (const float*)d_in[19];
    const float* dbhh  = (const float*)d_in[20];
    const float* Wout  = (const float*)d_in[21];
    const float* bout  = (const float*)d_in[22];
    const float* Wseq  = (const float*)d_in[23];
    const float* bseq  = (const float*)d_in[24];
    const float* Wseq2 = (const float*)d_in[25];
    const float* bseq2 = (const float*)d_in[26];

    float* recon  = out;                 // [16384][100][5] f32
    float* out_mu = out + 8192000;       // [16384]
    float* out_lv = out_mu + 16384;      // [16384]
    float* out_nm = out_lv + 16384;      // [16384]

    vae_mfma5_kernel<<<512, 256, 0, stream>>>(x, eps,
        eWih, eWhh, ebih, ebhh, Wmu, bmu, Wlv, blv,
        Wl2h, bl2h, Wl2h2, bl2h2, stok, Wemb, bemb,
        dWih, dWhh, dbih, dbhh, Wout, bout,
        Wseq, bseq, Wseq2, bseq2,
        recon, out_mu, out_lv, out_nm);
}

// Round 15
// 142.886 us; speedup vs baseline: 1.4582x; 1.4582x over previous
//
#include <hip/hip_runtime.h>
#include <hip/hip_bf16.h>

typedef short bf16x8 __attribute__((ext_vector_type(8)));
typedef float f32x4  __attribute__((ext_vector_type(4)));
typedef unsigned int u32x4 __attribute__((ext_vector_type(4)));

#define LOG2E 1.44269504088896340736f

static __device__ __forceinline__ unsigned short f2bf(float f){
    __hip_bfloat16 h = __float2bfloat16(f);
    return __builtin_bit_cast(unsigned short, h);
}
static __device__ __forceinline__ unsigned pk_bf16(float lo, float hi){
    return (((unsigned)f2bf(hi)) << 16) | (unsigned)f2bf(lo);
}
static __device__ __forceinline__ float rcp_(float x){ return __builtin_amdgcn_rcpf(x); }
static __device__ __forceinline__ float ex2(float x){ return __builtin_amdgcn_exp2f(x); }
static __device__ __forceinline__ f32x4 mfma16(bf16x8 a, bf16x8 b, f32x4 c){
    return __builtin_amdgcn_mfma_f32_16x16x32_bf16(a, b, c, 0, 0, 0);
}
static __device__ __forceinline__ unsigned relu_pk(unsigned v){
    unsigned m = ((v >> 15) & 0x00010001u) * 0xFFFFu;
    return v & ~m;
}

__global__ void marker_kernel(float* out, int n, float v){
    int i = blockIdx.x * 256 + threadIdx.x;
    if (i < n) out[i] = v;
}

// v6: unit-split wave pair. A pair of waves shares 16 batch rows; wave W
// computes gates only for units W*16..W*16+15 (4 MFMA blocks, 28 trans/step
// -- half of v3), so the PAIR does exactly v3's work with no duplication.
// h is exchanged through a double-buffered LDS array with one barrier per
// step. 512 blocks x 4 waves = 2 waves/SIMD: the co-resident block hides
// the dependency stalls that v3 (1 wave/SIMD) exposed.
__global__ __launch_bounds__(256, 2)
void vae_mfma6_kernel(const float* __restrict__ x,      const float* __restrict__ eps,
                      const float* __restrict__ eWih,   const float* __restrict__ eWhh,
                      const float* __restrict__ ebih,   const float* __restrict__ ebhh,
                      const float* __restrict__ Wmu,    const float* __restrict__ bmu,
                      const float* __restrict__ Wlv,    const float* __restrict__ blv,
                      const float* __restrict__ Wl2h,   const float* __restrict__ bl2h,
                      const float* __restrict__ Wl2h2,  const float* __restrict__ bl2h2,
                      const float* __restrict__ stok,   const float* __restrict__ Wemb,
                      const float* __restrict__ bemb,
                      const float* __restrict__ dWih,   const float* __restrict__ dWhh,
                      const float* __restrict__ dbih,   const float* __restrict__ dbhh,
                      const float* __restrict__ Wout,   const float* __restrict__ bout,
                      const float* __restrict__ Wseq,   const float* __restrict__ bseq,
                      const float* __restrict__ Wseq2,  const float* __restrict__ bseq2,
                      float* __restrict__ recon,
                      float* __restrict__ out_mu,
                      float* __restrict__ out_lv,
                      float* __restrict__ out_num)
{
    __shared__ unsigned hx[2][2][16][20];  // [parity][pair][batch col][word 0..15 (+4 pad)]
    __shared__ float hbf[2][16][33];
    __shared__ float cbf[2][16][33];
    __shared__ float mubuf[2][16];
    __shared__ float x0buf[32];
    __shared__ float cw[524];
    // cw: 0 Wmu[64] | 64 Wlv[64] | 128 Wseq[32] | 160 bseq[32] | 192 Wseq2[32]
    //     224 Wl2h[32] | 256 bl2h[32] | 288 Wl2h2[32] | 320 bl2h2[32]
    //     352 Wout[160] | 512 bout[5] | 517 bmu | 518 blv | 519 bseq2

    const int tid = threadIdx.x;
    const int w   = tid >> 6;
    const int W   = w & 1;      // unit half owned by this wave (units W*16..+15)
    const int pi  = w >> 1;     // pair index within block
    const int l   = tid & 63;
    const int c   = l & 15;     // batch col / A-frag row
    const int g   = l >> 4;     // k-chunk / D row-group
    const int bbase = blockIdx.x * 32 + pi * 16;

    if (tid < 64){ cw[tid] = Wmu[tid]; cw[64+tid] = Wlv[tid]; }
    if (tid < 32){
        cw[128+tid] = Wseq[tid];  cw[160+tid] = bseq[tid];  cw[192+tid] = Wseq2[tid];
        cw[224+tid] = Wl2h[tid];  cw[256+tid] = bl2h[tid];
        cw[288+tid] = Wl2h2[tid]; cw[320+tid] = bl2h2[tid];
    }
    if (tid < 160) cw[352+tid] = Wout[tid];
    if (tid < 5)   cw[512+tid] = bout[tid];
    if (tid == 0){ cw[517] = bmu[0]; cw[518] = blv[0]; cw[519] = bseq2[0]; }

    // ---- encoder fragments: wave W covers gate rows n*32 + W*16 + r ----
    bf16x8 WH[4], WX[4];
    f32x4  biasv[4];
    #pragma unroll
    for (int n=0;n<4;++n){
        const float sc = (n==2) ? (-2.0f*LOG2E) : (-LOG2E);
        const int GR = n*32 + W*16 + c;
        bf16x8 t;
        #pragma unroll
        for (int j=0;j<8;++j) t[j] = (short)f2bf(sc * eWhh[(size_t)GR*32 + g*8 + j]);
        WH[n] = t;
        bf16x8 tx = (bf16x8)0;
        if (g == 0){
            #pragma unroll
            for (int j=0;j<5;++j) tx[j] = (short)f2bf(sc * eWih[(size_t)GR*5 + j]);
        }
        WX[n] = tx;
        f32x4 b4;
        #pragma unroll
        for (int q=0;q<4;++q){
            const int R = n*32 + W*16 + g*4 + q;
            b4[q] = sc * (ebih[R] + ebhh[R]);
        }
        biasv[n] = b4;
    }

    float cs[4], hn[4];
    #pragma unroll
    for (int k=0;k<4;++k){ cs[k] = 0.0f; hn[k] = 0.0f; }

    // prefill h(0) = 0 into parity-0 buffer (each lane writes its 2 words)
    *(uint2*)&hx[0][pi][c][W*8 + g*2] = make_uint2(0u, 0u);
    int p = 0;
    __syncthreads();     // also covers cw

    float4 xA = {0,0,0,0}; float xB = 0.0f;
    if (g == 0){
        const float* xp = x + (size_t)(bbase+c)*500;
        xA = *(const float4*)xp; xB = xp[4];
    }

    // ================= encoder LSTM (T=100) =================
    for (int t=0; t<100; ++t){
        u32x4 hw = *(const u32x4*)&hx[p][pi][c][g*4];   // full h words g*4..+3
        bf16x8 bh = __builtin_bit_cast(bf16x8, hw);

        bf16x8 bx = (bf16x8)0;
        if (g == 0){
            bx[0]=(short)f2bf(xA.x); bx[1]=(short)f2bf(xA.y);
            bx[2]=(short)f2bf(xA.z); bx[3]=(short)f2bf(xA.w);
            bx[4]=(short)f2bf(xB);
            if (t < 99){
                const float* xp = x + (size_t)(bbase+c)*500 + (t+1)*5;
                xA = *(const float4*)xp; xB = xp[4];
            }
        }

        f32x4 acc[4];
        #pragma unroll
        for (int n=0;n<4;++n) acc[n] = mfma16(WX[n], bx, biasv[n]);   // independent of h-read
        #pragma unroll
        for (int n=0;n<4;++n) acc[n] = mfma16(WH[n], bh, acc[n]);

        #pragma unroll
        for (int q=0;q<4;++q){
            float ei = ex2(acc[0][q]);      // e^{-i}
            float ef = ex2(acc[1][q]);      // e^{-f}
            float eg = ex2(acc[2][q]);      // e^{-2g}
            float eo = ex2(acc[3][q]);      // e^{-o}
            float pig = (1.0f+ei)*(1.0f+eg);
            float num = cs[q]*pig + (1.0f+ef)*(1.0f-eg);
            float cn  = num * rcp_((1.0f+ef)*pig);
            float ec  = ex2(cn * (-2.0f*LOG2E));
            hn[q]     = (1.0f-ec) * rcp_((1.0f+eo)*(1.0f+ec));
            cs[q]     = cn;
        }
        *(uint2*)&hx[p^1][pi][c][W*8 + g*2] =
            make_uint2(pk_bf16(hn[0], hn[1]), pk_bf16(hn[2], hn[3]));
        __syncthreads();
        p ^= 1;
    }

    // ---- stage h_n / c_n (own 4 units) for heads ----
    #pragma unroll
    for (int q=0;q<4;++q){
        const int U = W*16 + g*4 + q;
        hbf[pi][c][U] = hn[q];
        cbf[pi][c][U] = cs[q];
    }
    __syncthreads();

    // ---- decoder fragments ----
    bf16x8 WI[4], WHd[4];
    f32x4  dbias[4];
    #pragma unroll
    for (int n=0;n<4;++n){
        const float sc = (n==2) ? (-2.0f*LOG2E) : (-LOG2E);
        const int GR = n*32 + W*16 + c;
        bf16x8 ti, th;
        #pragma unroll
        for (int j=0;j<8;++j){
            ti[j] = (short)f2bf(sc * dWih[(size_t)GR*32 + g*8 + j]);
            th[j] = (short)f2bf(sc * dWhh[(size_t)GR*32 + g*8 + j]);
        }
        WI[n] = ti; WHd[n] = th;
        f32x4 b4;
        #pragma unroll
        for (int q=0;q<4;++q){
            const int R = n*32 + W*16 + g*4 + q;
            b4[q] = sc * (dbih[R] + dbhh[R]);
        }
        dbias[n] = b4;
    }
    bf16x8 WO = (bf16x8)0;
    f32x4 bosv = (f32x4)0;
    if (c < 5){
        bf16x8 to;
        #pragma unroll
        for (int j=0;j<8;++j) to[j] = (short)f2bf(Wout[c*32 + g*8 + j]);
        WO = to;
    }
    #pragma unroll
    for (int q=0;q<4;++q){
        const int dd = g*4 + q;
        bosv[q] = (dd < 5) ? bout[dd] : 0.0f;
    }

    // ---- heads: 32 batch rows per block, one thread each ----
    if (tid < 32){
        const int pr = tid >> 4, rr = tid & 15;
        const int row = blockIdx.x*32 + tid;
        float mu = cw[517], lv = cw[518];
        #pragma unroll
        for (int k=0;k<32;++k){
            float hvv = hbf[pr][rr][k], cvv = cbf[pr][rr][k];
            mu += hvv*cw[k]    + cvv*cw[32+k];
            lv += hvv*cw[64+k] + cvv*cw[96+k];
        }
        out_mu[row] = mu;
        out_lv[row] = lv;
        mubuf[pr][rr] = mu;
        float z = mu + eps[row] * __builtin_amdgcn_exp2f(0.5f*LOG2E*lv);
        float a2 = cw[519];
        #pragma unroll
        for (int j=0;j<32;++j){
            float s = z*cw[128+j] + cw[160+j];
            s = s > 0.0f ? s : 0.01f*s;
            a2 += cw[192+j]*s;
        }
        out_num[row] = fmaxf(a2, 0.0f);
        // x0 = relu(start_token @ Wemb^T + bemb), batch-independent
        float v = bemb[tid];
        #pragma unroll
        for (int d=0; d<5; ++d) v += stok[d]*Wemb[tid*5 + d];
        x0buf[tid] = fmaxf(v, 0.0f);
    }
    __syncthreads();

    // ---- decoder init: own c0; own 4 h0 units packed into the exchange buf ----
    {
        const float muv = mubuf[pi][c];
        float h4[4];
        #pragma unroll
        for (int q=0;q<4;++q){
            const int U = W*16 + g*4 + q;
            float a = muv*cw[224+U] + cw[256+U];
            float b = muv*cw[288+U] + cw[320+U];
            h4[q]  = (a > 0.0f ? a : 0.01f*a);
            cs[q]  = (b > 0.0f ? b : 0.01f*b);
        }
        *(uint2*)&hx[0][pi][c][W*8 + g*2] =
            make_uint2(pk_bf16(h4[0], h4[1]), pk_bf16(h4[2], h4[3]));
    }
    p = 0;
    __syncthreads();

    bf16x8 bx0;
    #pragma unroll
    for (int j=0;j<8;++j) bx0[j] = (short)f2bf(x0buf[g*8 + j]);

    // ================= decoder LSTM (T=100, autoregressive) =================
    for (int t=0; t<100; ++t){
        u32x4 hw = *(const u32x4*)&hx[p][pi][c][g*4];
        bf16x8 bh = __builtin_bit_cast(bf16x8, hw);

        bf16x8 bx;
        if (t == 0) bx = bx0;
        else {
            u32x4 rv;
            #pragma unroll
            for (int i=0;i<4;++i) rv[i] = relu_pk(hw[i]);
            bx = __builtin_bit_cast(bf16x8, rv);
        }

        f32x4 acc[4];
        #pragma unroll
        for (int n=0;n<4;++n) acc[n] = mfma16(WI[n], bx, dbias[n]);
        #pragma unroll
        for (int n=0;n<4;++n) acc[n] = mfma16(WHd[n], bh, acc[n]);

        if (W == 0 && t > 0){    // recon row t-1 = Wout @ h_t (wave A only)
            f32x4 ao = mfma16(WO, bh, bosv);
            float* rp = recon + (size_t)(bbase+c)*500 + (t-1)*5;
            if (g == 0){ rp[0]=ao[0]; rp[1]=ao[1]; rp[2]=ao[2]; rp[3]=ao[3]; }
            else if (g == 1){ rp[4]=ao[0]; }
        }

        #pragma unroll
        for (int q=0;q<4;++q){
            float ei = ex2(acc[0][q]);
            float ef = ex2(acc[1][q]);
            float eg = ex2(acc[2][q]);
            float eo = ex2(acc[3][q]);
            float pig = (1.0f+ei)*(1.0f+eg);
            float num = cs[q]*pig + (1.0f+ef)*(1.0f-eg);
            float cn  = num * rcp_((1.0f+ef)*pig);
            float ec  = ex2(cn * (-2.0f*LOG2E));
            hn[q]     = (1.0f-ec) * rcp_((1.0f+eo)*(1.0f+ec));
            cs[q]     = cn;
        }
        *(uint2*)&hx[p^1][pi][c][W*8 + g*2] =
            make_uint2(pk_bf16(hn[0], hn[1]), pk_bf16(hn[2], hn[3]));
        __syncthreads();
        p ^= 1;
    }

    // final recon row 99 from h_100
    if (W == 0){
        u32x4 hw = *(const u32x4*)&hx[p][pi][c][g*4];
        f32x4 ao = mfma16(WO, __builtin_bit_cast(bf16x8, hw), bosv);
        float* rp = recon + (size_t)(bbase+c)*500 + 99*5;
        if (g == 0){ rp[0]=ao[0]; rp[1]=ao[1]; rp[2]=ao[2]; rp[3]=ao[3]; }
        else if (g == 1){ rp[4]=ao[0]; }
    }
}

extern "C" void kernel_launch(void* const* d_in, const int* in_sizes, int n_in,
                              void* d_out, int out_size, void* d_ws, size_t ws_size,
                              hipStream_t stream)
{
    (void)d_ws; (void)ws_size;
    static const int EXPECT[27] = {8192000,16384,640,4096,128,128,64,1,64,1,
                                   32,32,32,32,5,160,32,4096,4096,128,128,
                                   160,5,32,32,32,1};
    bool in_ok = (n_in == 27);
    if (in_ok) for (int i = 0; i < 27; ++i) in_ok = in_ok && (in_sizes[i] == EXPECT[i]);
    bool out_ok = (out_size == 8241152);

    float* out = (float*)d_out;
    if (!in_ok){
        marker_kernel<<<(out_size + 255)/256, 256, 0, stream>>>(out, out_size, 2.0f);
        return;
    }
    if (!out_ok){
        marker_kernel<<<(out_size + 255)/256, 256, 0, stream>>>(out, out_size, 3.0f);
        return;
    }

    const float* x     = (const float*)d_in[0];
    const float* eps   = (const float*)d_in[1];
    const float* eWih  = (const float*)d_in[2];
    const float* eWhh  = (const float*)d_in[3];
    const float* ebih  = (const float*)d_in[4];
    const float* ebhh  = (const float*)d_in[5];
    const float* Wmu   = (const float*)d_in[6];
    const float* bmu   = (const float*)d_in[7];
    const float* Wlv   = (const float*)d_in[8];
    const float* blv   = (const float*)d_in[9];
    const float* Wl2h  = (const float*)d_in[10];
    const float* bl2h  = (const float*)d_in[11];
    const float* Wl2h2 = (const float*)d_in[12];
    const float* bl2h2 = (const float*)d_in[13];
    const float* stok  = (const float*)d_in[14];
    const float* Wemb  = (const float*)d_in[15];
    const float* bemb  = (const float*)d_in[16];
    const float* dWih  = (const float*)d_in[17];
    const float* dWhh  = (const float*)d_in[18];
    const float* dbih  = (const float*)d_in[19];
    const float* dbhh  = (const float*)d_in[20];
    const float* Wout  = (const float*)d_in[21];
    const float* bout  = (const float*)d_in[22];
    const float* Wseq  = (const float*)d_in[23];
    const float* bseq  = (const float*)d_in[24];
    const float* Wseq2 = (const float*)d_in[25];
    const float* bseq2 = (const float*)d_in[26];

    float* recon  = out;                 // [16384][100][5] f32
    float* out_mu = out + 8192000;       // [16384]
    float* out_lv = out_mu + 16384;      // [16384]
    float* out_nm = out_lv + 16384;      // [16384]

    vae_mfma6_kernel<<<512, 256, 0, stream>>>(x, eps,
        eWih, eWhh, ebih, ebhh, Wmu, bmu, Wlv, blv,
        Wl2h, bl2h, Wl2h2, bl2h2, stok, Wemb, bemb,
        dWih, dWhh, dbih, dbhh, Wout, bout,
        Wseq, bseq, Wseq2, bseq2,
        recon, out_mu, out_lv, out_nm);
}